// Round 2
// baseline (8424.028 us; speedup 1.0000x reference)
//
#include <hip/hip_runtime.h>
#include <cmath>

// Problem constants
constexpr int NB = 16;            // batch
constexpr int NT = 2048;          // seq len
constexpr int ND = 512;           // embed dim
constexpr int NL = 6;             // layers
constexpr int NH = 1024;          // mlp hidden
constexpr int NK = 256;           // freq bands kept
constexpr int NM = NB * NT;       // 32768 rows

constexpr float PI2 = 6.283185307179586f;

__device__ __forceinline__ float gelu_exact(float v) {
    return 0.5f * v * (1.0f + erff(v * 0.70710678118654752f));
}

__device__ __forceinline__ float block_sum256(float val, float* lds4) {
#pragma unroll
    for (int o = 32; o > 0; o >>= 1) val += __shfl_down(val, o);
    int lane = threadIdx.x & 63, wid = threadIdx.x >> 6;
    if (lane == 0) lds4[wid] = val;
    __syncthreads();
    float t = lds4[0] + lds4[1] + lds4[2] + lds4[3];
    __syncthreads();
    return t;
}

// ---------------- K1: direct DFT of byte signal, 16x256 bins -----------------
__global__ void dft_kernel(const int* __restrict__ bytes, const float* __restrict__ fb,
                           float* __restrict__ mag, float* __restrict__ cph,
                           float* __restrict__ sph) {
    __shared__ float lr[4], li[4];
    int b = blockIdx.x, f = blockIdx.y;
    float re = 0.f, im = 0.f;
    for (int t = threadIdx.x; t < NT; t += 256) {
        float s = (float)bytes[b * NT + t] * (1.0f / 127.5f) - 1.0f;
        int idx = (t * f) & (NT - 1);
        float a = (float)idx * (PI2 / NT);
        float sn, cs;
        sincosf(a, &sn, &cs);
        re += s * cs;
        im -= s * sn;
    }
#pragma unroll
    for (int o = 32; o > 0; o >>= 1) {
        re += __shfl_down(re, o);
        im += __shfl_down(im, o);
    }
    int lane = threadIdx.x & 63, wid = threadIdx.x >> 6;
    if (lane == 0) { lr[wid] = re; li[wid] = im; }
    __syncthreads();
    if (threadIdx.x == 0) {
        float R = lr[0] + lr[1] + lr[2] + lr[3];
        float I = li[0] + li[1] + li[2] + li[3];
        float m = sqrtf(R * R + I * I);
        mag[b * NK + f] = m * fb[f];
        float inv = (m > 0.f) ? 1.0f / m : 0.f;
        cph[b * NK + f] = (m > 0.f) ? R * inv : 1.0f;  // cos(angle)
        sph[b * NK + f] = I * inv;                     // sin(angle)
    }
}

// ---------------- K2: spectral features [mag | sin(phase)] -------------------
__global__ void feats_kernel(const float* __restrict__ mag, const float* __restrict__ cph,
                             const float* __restrict__ sph, float* __restrict__ feats) {
    int idx = blockIdx.x * 256 + threadIdx.x;
    int d = idx & (ND - 1);
    int m = idx >> 9;
    int b = m >> 11, t = m & (NT - 1);
    float v;
    if (d < NK) {
        v = mag[b * NK + d];
    } else {
        int f = d - NK;
        int a = (t * f) & (NT - 1);
        float sn, cs;
        sincosf((float)a * (PI2 / NT), &sn, &cs);
        v = sph[b * NK + f] * cs + cph[b * NK + f] * sn;  // sin(bp + theta)
    }
    feats[idx] = v;
}

// ---------------- LayerNorm (optionally fused GELU) --------------------------
template <int NV, int GELU>
__global__ void ln_kernel(const float* __restrict__ in, const float* __restrict__ g,
                          const float* __restrict__ bta, float* __restrict__ out) {
    __shared__ float lds4[4];
    constexpr int NE = NV / 256;
    size_t row = blockIdx.x;
    const float* p = in + row * NV;
    float v[NE];
    float sum = 0.f;
#pragma unroll
    for (int i = 0; i < NE; ++i) {
        v[i] = p[threadIdx.x + 256 * i];
        sum += v[i];
    }
    sum = block_sum256(sum, lds4);
    float mean = sum * (1.0f / NV);
    float sq = 0.f;
#pragma unroll
    for (int i = 0; i < NE; ++i) {
        float d = v[i] - mean;
        sq += d * d;
    }
    sq = block_sum256(sq, lds4);
    float inv = rsqrtf(sq * (1.0f / NV) + 1e-5f);
    float* o = out + row * NV;
#pragma unroll
    for (int i = 0; i < NE; ++i) {
        int c = threadIdx.x + 256 * i;
        float r = (v[i] - mean) * inv * g[c] + bta[c];
        if (GELU) r = gelu_exact(r);
        o[c] = r;
    }
}

// ---------------- FFT along D (512-pt, per row), hermitian-packed output -----
// P[row][0..256]   = Zr[0..256]
// P[row][257..511] = Zi[1..255]     (Zi[0] == Zi[256] == 0 exactly)
__global__ void fft_d512_kernel(const float* __restrict__ y, float* __restrict__ P) {
    __shared__ float sr[2][512], si[2][512];
    int sub = threadIdx.x >> 7;
    int tid = threadIdx.x & 127;
    size_t row = (size_t)blockIdx.x * 2 + sub;
    const float* p = y + row * ND;
    for (int i = tid; i < 512; i += 128) {
        int r = __brev((unsigned)i) >> 23;  // 9-bit reverse
        sr[sub][r] = p[i];
        si[sub][r] = 0.f;
    }
    __syncthreads();
    for (int len = 2; len <= 512; len <<= 1) {
        int half = len >> 1;
        for (int q = tid; q < 256; q += 128) {
            int k = q & (half - 1);
            int j = ((q - k) << 1) + k;
            float a = -PI2 * (float)k / (float)len;
            float sn = __sinf(a), cs = __cosf(a);
            float ur = sr[sub][j], ui = si[sub][j];
            float vr = sr[sub][j + half], vi = si[sub][j + half];
            float tr = vr * cs - vi * sn;
            float ti = vr * sn + vi * cs;
            sr[sub][j] = ur + tr;
            si[sub][j] = ui + ti;
            sr[sub][j + half] = ur - tr;
            si[sub][j + half] = ui - ti;
        }
        __syncthreads();
    }
    float* out = P + row * ND;
    for (int i = tid; i < 512; i += 128)
        out[i] = (i <= 256) ? sr[sub][i] : si[sub][i - 256];
}

// ---------------- tiled transpose: PT[b][idx][t] = P[b*T+t][idx] -------------
__global__ void transpose_bt_kernel(const float* __restrict__ P, float* __restrict__ PT) {
    __shared__ float tile[32][33];
    int b = blockIdx.z, t0 = blockIdx.x * 32, d0 = blockIdx.y * 32;
    int j = threadIdx.x & 31, i0 = threadIdx.x >> 5;
    for (int i = i0; i < 32; i += 8)
        tile[i][j] = P[((size_t)(b * NT + t0 + i)) * ND + d0 + j];
    __syncthreads();
    for (int i = i0; i < 32; i += 8)
        PT[((size_t)(b * ND + d0 + i)) * NT + t0 + j] = tile[j][i];
}

// ---------------- FFT along T (2048-pt per column d=0..256) ------------------
// Writes Mt[b][d][t] = Re C_d[t]; and for 1<=d<=255: Mt[b][512-d][t] = Re C_d[(T-t)%T]
__global__ void fft_t2048_kernel(const float* __restrict__ PT, float* __restrict__ Mt) {
    __shared__ float sr[2048], si[2048];  // 16 KiB
    int b = blockIdx.x;
    int d = blockIdx.y;  // 0..256
    const float* zr = PT + ((size_t)(b * ND + d)) * NT;
    const float* zi = PT + ((size_t)(b * ND + 256 + d)) * NT;  // valid for 1<=d<=255
    bool has_im = (d != 0) && (d != 256);
    for (int t = threadIdx.x; t < 2048; t += 256) {
        int r = __brev((unsigned)t) >> 21;  // 11-bit reverse
        sr[r] = zr[t];
        si[r] = has_im ? zi[t] : 0.f;
    }
    __syncthreads();
    for (int len = 2; len <= 2048; len <<= 1) {
        int half = len >> 1;
        for (int q = threadIdx.x; q < 1024; q += 256) {
            int k = q & (half - 1);
            int j = ((q - k) << 1) + k;
            float a = -PI2 * (float)k / (float)len;
            float sn = __sinf(a), cs = __cosf(a);
            float ur = sr[j], ui = si[j];
            float vr = sr[j + half], vi = si[j + half];
            float tr = vr * cs - vi * sn;
            float ti = vr * sn + vi * cs;
            sr[j] = ur + tr;
            si[j] = ui + ti;
            sr[j + half] = ur - tr;
            si[j + half] = ui - ti;
        }
        __syncthreads();
    }
    float* m0 = Mt + ((size_t)(b * ND + d)) * NT;
    for (int t = threadIdx.x; t < 2048; t += 256) m0[t] = sr[t];
    if (has_im) {
        float* m1 = Mt + ((size_t)(b * ND + (512 - d))) * NT;
        for (int t = threadIdx.x; t < 2048; t += 256) m1[t] = sr[(2048 - t) & 2047];
    }
}

// ---------------- x[b,t,d] += Mt[b,d,t] (tiled transpose-add) ----------------
__global__ void add_transpose_kernel(const float* __restrict__ Mt, float* __restrict__ x) {
    __shared__ float tile[32][33];
    int b = blockIdx.z, t0 = blockIdx.x * 32, d0 = blockIdx.y * 32;
    int j = threadIdx.x & 31, i0 = threadIdx.x >> 5;
    for (int i = i0; i < 32; i += 8)
        tile[i][j] = Mt[((size_t)(b * ND + d0 + i)) * NT + t0 + j];
    __syncthreads();
    for (int i = i0; i < 32; i += 8) {
        size_t xi = ((size_t)(b * NT + t0 + i)) * ND + d0 + j;
        x[xi] += tile[j][i];
    }
}

// ---------------- f32 tiled GEMM: C = [gelu](A@W [+ bias]) [+ C] -------------
template <int GELU, int ACC, int ADDB>
__global__ void gemm_kernel(const float* __restrict__ A, const float* __restrict__ W,
                            const float* __restrict__ bias, float* __restrict__ C,
                            int Kdim, int lda, int ldw, int ldc) {
    __shared__ float As[16][68];
    __shared__ float Bs[16][68];
    int row0 = blockIdx.x * 64;
    int col0 = blockIdx.y * 64;
    int tid = threadIdx.x;
    int tx = tid & 15, ty = tid >> 4;
    float acc[4][4] = {};
    for (int k0 = 0; k0 < Kdim; k0 += 16) {
#pragma unroll
        for (int rep = 0; rep < 4; ++rep) {
            int lin = rep * 256 + tid;
            int r = lin >> 4, kk = lin & 15;
            As[kk][r] = A[(size_t)(row0 + r) * lda + k0 + kk];
            int kb = lin >> 6, n = lin & 63;
            Bs[kb][n] = W[(size_t)(k0 + kb) * ldw + col0 + n];
        }
        __syncthreads();
#pragma unroll
        for (int k = 0; k < 16; ++k) {
            float4 av = *(const float4*)&As[k][ty * 4];
            float4 bv = *(const float4*)&Bs[k][tx * 4];
            float ar[4] = {av.x, av.y, av.z, av.w};
            float br[4] = {bv.x, bv.y, bv.z, bv.w};
#pragma unroll
            for (int i = 0; i < 4; ++i)
#pragma unroll
                for (int jj = 0; jj < 4; ++jj)
                    acc[i][jj] = fmaf(ar[i], br[jj], acc[i][jj]);
        }
        __syncthreads();
    }
#pragma unroll
    for (int i = 0; i < 4; ++i) {
        size_t off = (size_t)(row0 + ty * 4 + i) * ldc + col0 + tx * 4;
        float4 old;
        if (ACC) old = *(const float4*)&C[off];
        float4 r;
        float* rp = (float*)&r;
#pragma unroll
        for (int jj = 0; jj < 4; ++jj) {
            float v = acc[i][jj];
            if (ADDB) v += bias[col0 + tx * 4 + jj];
            if (GELU) v = gelu_exact(v);
            rp[jj] = v;
        }
        if (ACC) { r.x += old.x; r.y += old.y; r.z += old.z; r.w += old.w; }
        *(float4*)&C[off] = r;
    }
}

extern "C" void kernel_launch(void* const* d_in, const int* in_sizes, int n_in,
                              void* d_out, int out_size, void* d_ws, size_t ws_size,
                              hipStream_t stream) {
    const int* byte_ids    = (const int*)d_in[0];
    const float* freq_bands = (const float*)d_in[1];
    const float* fp_w1   = (const float*)d_in[2];
    const float* fp_b1   = (const float*)d_in[3];
    const float* fp_ln_g = (const float*)d_in[4];
    const float* fp_ln_b = (const float*)d_in[5];
    const float* fp_w2   = (const float*)d_in[6];
    const float* fp_b2   = (const float*)d_in[7];
    const float* blk_ln1_g = (const float*)d_in[8];
    const float* blk_ln1_b = (const float*)d_in[9];
    const float* blk_ln2_g = (const float*)d_in[10];
    const float* blk_ln2_b = (const float*)d_in[11];
    const float* blk_w1  = (const float*)d_in[12];
    const float* blk_b1  = (const float*)d_in[13];
    const float* blk_w2  = (const float*)d_in[14];
    const float* blk_b2  = (const float*)d_in[15];
    const float* norm_g  = (const float*)d_in[16];
    const float* norm_b  = (const float*)d_in[17];
    const float* out_w   = (const float*)d_in[18];
    const float* out_b   = (const float*)d_in[19];
    float* out = (float*)d_out;
    float* ws = (float*)d_ws;

    // Workspace: exactly 3*MD floats = 192 MiB, all small arrays inside.
    const size_t MD = (size_t)NM * ND;  // 16.78M floats (64 MiB)
    float* A = ws;              // slot A: feats -> x
    float* Bu = ws + MD;        // slot B: y / PT
    float* S = ws + 2 * MD;     // slot S: packed Z / Mt / h-chunk
    // small arrays live at the tail of S; dead before S is first written
    float* mag = S + MD - 3 * (size_t)(NB * NK);
    float* cph = mag + NB * NK;
    float* sph = cph + NB * NK;
    // freq_proj hidden h [M,1024] spans slots B+S (feats lives in A meanwhile)
    float* h = Bu;

    // 1) spectral embedding -> feats in A
    dft_kernel<<<dim3(NB, NK), 256, 0, stream>>>(byte_ids, freq_bands, mag, cph, sph);
    feats_kernel<<<(NM * ND) / 256, 256, 0, stream>>>(mag, cph, sph, A);

    // 2) freq_proj: Linear(512->1024) -> LN -> GELU -> Linear(1024->512) -> x in A
    gemm_kernel<0, 0, 1><<<dim3(NM / 64, NH / 64), 256, 0, stream>>>(
        A, fp_w1, fp_b1, h, ND, ND, NH, NH);
    ln_kernel<NH, 1><<<NM, 256, 0, stream>>>(h, fp_ln_g, fp_ln_b, h);
    gemm_kernel<0, 0, 1><<<dim3(NM / 64, ND / 64), 256, 0, stream>>>(
        h, fp_w2, fp_b2, A, NH, NH, ND, ND);

    float* x = A;
    float* y = Bu;

    // 3) spectral MLP blocks
    for (int l = 0; l < NL; ++l) {
        ln_kernel<ND, 0><<<NM, 256, 0, stream>>>(x, blk_ln1_g + l * ND, blk_ln1_b + l * ND, y);
        fft_d512_kernel<<<NM / 2, 256, 0, stream>>>(y, S);                 // packed Z in S
        transpose_bt_kernel<<<dim3(NT / 32, ND / 32, NB), 256, 0, stream>>>(S, Bu);  // PT in B
        fft_t2048_kernel<<<dim3(NB, 257), 256, 0, stream>>>(Bu, S);        // Mt in S
        add_transpose_kernel<<<dim3(NT / 32, ND / 32, NB), 256, 0, stream>>>(S, x);
        ln_kernel<ND, 0><<<NM, 256, 0, stream>>>(x, blk_ln2_g + l * ND, blk_ln2_b + l * ND, y);
        const float* W1 = blk_w1 + (size_t)l * ND * NH;
        const float* W2 = blk_w2 + (size_t)l * NH * ND;
        const float* b1 = blk_b1 + (size_t)l * NH;
        const float* b2 = blk_b2 + (size_t)l * ND;
        // chunk 0: hidden cols 0..511
        gemm_kernel<1, 0, 1><<<dim3(NM / 64, 512 / 64), 256, 0, stream>>>(
            y, W1, b1, S, ND, ND, NH, 512);
        gemm_kernel<0, 1, 1><<<dim3(NM / 64, ND / 64), 256, 0, stream>>>(
            S, W2, b2, x, 512, 512, ND, ND);
        // chunk 1: hidden cols 512..1023
        gemm_kernel<1, 0, 1><<<dim3(NM / 64, 512 / 64), 256, 0, stream>>>(
            y, W1 + 512, b1 + 512, S, ND, ND, NH, 512);
        gemm_kernel<0, 1, 0><<<dim3(NM / 64, ND / 64), 256, 0, stream>>>(
            S, W2 + (size_t)512 * ND, b2, x, 512, 512, ND, ND);
    }

    // 4) final norm + head
    ln_kernel<ND, 0><<<NM, 256, 0, stream>>>(x, norm_g, norm_b, y);
    gemm_kernel<0, 0, 1><<<dim3(NM / 64, 256 / 64), 256, 0, stream>>>(
        y, out_w, out_b, out, ND, ND, 256, 256);
}